// Round 5
// baseline (600.669 us; speedup 1.0000x reference)
//
#include <hip/hip_runtime.h>

typedef __attribute__((ext_vector_type(2))) float f32x2;
typedef __attribute__((ext_vector_type(4))) float f32x4;
typedef __attribute__((ext_vector_type(16))) float f32x16;
typedef __attribute__((ext_vector_type(8))) short bf16x8;
typedef __attribute__((ext_vector_type(8))) unsigned short u16x8;

#define GL2LDS(g, l) __builtin_amdgcn_global_load_lds( \
    (const __attribute__((address_space(1))) void*)(g), \
    (__attribute__((address_space(3))) void*)(l), 16, 0, 0)

__device__ __forceinline__ unsigned short f2bf(float x) {
    union { float f; unsigned u; } v; v.f = x;
    unsigned r = (v.u + 0x7FFF + ((v.u >> 16) & 1)) >> 16;
    return (unsigned short)r;
}

// ---------------- Kernel 1 (fused): blocks [0,640): Wc masked expert-sum;
// blocks [640, 17024): x fp32 -> bf16 conversion. The two are independent.
__global__ __launch_bounds__(256) void k_prep(const float* __restrict__ c0,
                                              const float* __restrict__ c1,
                                              const int* __restrict__ m0,
                                              const int* __restrict__ m1,
                                              float* __restrict__ Wc,
                                              const float* __restrict__ x,
                                              unsigned short* __restrict__ xb) {
    int b = blockIdx.x;
    if (b < 640) {
        int idx = b * 256 + threadIdx.x;
        if (idx >= 4096 * 40) return;
        int o = idx / 40, c = idx % 40;
        float s = 0.f;
        if (c < 32) {
            #pragma unroll
            for (int e = 0; e < 3; ++e) {
                int i = (e * 4096 + o) * 32 + c;
                s += c0[i] * (m0[i] != 0 ? 1.f : 0.f);
            }
        } else {
            int r = c - 32;
            #pragma unroll
            for (int e = 0; e < 3; ++e) {
                int i = (e * 4096 + o) * 8 + r;
                s += c1[i] * (m1[i] != 0 ? 1.f : 0.f);
            }
        }
        Wc[idx] = s;
    } else {
        int idx = (b - 640) * 256 + threadIdx.x;  // one per 8 elements; 4194304 total
        f32x4 f0 = ((const f32x4*)x)[(size_t)idx * 2];
        f32x4 f1 = ((const f32x4*)x)[(size_t)idx * 2 + 1];
        u16x8 o;
        o[0] = f2bf(f0[0]); o[1] = f2bf(f0[1]); o[2] = f2bf(f0[2]); o[3] = f2bf(f0[3]);
        o[4] = f2bf(f1[0]); o[5] = f2bf(f1[1]); o[6] = f2bf(f1[2]); o[7] = f2bf(f1[3]);
        *(u16x8*)(xb + (size_t)idx * 8) = o;
    }
}

// ---------------- Kernel 2: G[t][40] = 0.5 * (F @ Wc)[t][:]
__global__ __launch_bounds__(256) void k_gmat(const float* __restrict__ Wc,
                                              float* __restrict__ G) {
    __shared__ float lds[10752];  // staging: 128 f-rows x 84 floats; reused for reduction
    int tid = threadIdx.x;
    int t_base = blockIdx.x * 8;
    int f_slot = tid & 31;
    int tg = (tid >> 5) & 1;
    int rg = tid >> 6;
    float acc[4][10];
    #pragma unroll
    for (int a = 0; a < 4; ++a)
        #pragma unroll
        for (int b = 0; b < 10; ++b) acc[a][b] = 0.f;

    for (int ch = 0; ch < 16; ++ch) {
        __syncthreads();
        // stage 128 f-rows: row f_local <- Wc[(2f-1)*40 .. +80) (cos row || sin row)
        #pragma unroll
        for (int j = 0; j < 10; ++j) {
            int idx = tid + j * 256;        // 0..2559 float4 slots
            int row = idx / 20;
            int v = idx % 20;
            int f = ch * 128 + row;
            f32x4 val = {0.f, 0.f, 0.f, 0.f};
            if (f >= 1) val = *(const f32x4*)(Wc + (2 * f - 1) * 40 + v * 4);
            *(f32x4*)(lds + row * 84 + v * 4) = val;
        }
        __syncthreads();
        #pragma unroll
        for (int j2 = 0; j2 < 4; ++j2) {
            int f_local = f_slot + 32 * j2;
            int f = ch * 128 + f_local;
            float cs[4], sn[4];
            #pragma unroll
            for (int tt = 0; tt < 4; ++tt) {
                int t = t_base + tg * 4 + tt;
                int ph = (f * t) & 4095;                    // exact phase mod 2pi
                float rev = (float)ph * (1.0f / 4096.0f);   // revolutions, exact
                cs[tt] = __builtin_amdgcn_cosf(rev);        // cos(2*pi*rev)
                sn[tt] = __builtin_amdgcn_sinf(rev);
            }
            const float* Lc = lds + f_local * 84 + rg * 10;
            const float* Ls = Lc + 40;
            #pragma unroll
            for (int rr = 0; rr < 10; ++rr) {
                float wc = Lc[rr], ws = Ls[rr];
                #pragma unroll
                for (int tt = 0; tt < 4; ++tt)
                    acc[tt][rr] += cs[tt] * wc + sn[tt] * ws;
            }
        }
    }
    __syncthreads();
    #pragma unroll
    for (int tt = 0; tt < 4; ++tt)
        #pragma unroll
        for (int rr = 0; rr < 10; ++rr)
            lds[tid * 40 + tt * 10 + rr] = acc[tt][rr];
    __syncthreads();
    for (int oi = tid; oi < 320; oi += 256) {
        int t_local = oi / 40, rc = oi % 40;
        int tg2 = t_local >> 2, tsub = t_local & 3;
        int rg2 = rc / 10, rsub = rc % 10;
        float s = 0.f;
        #pragma unroll
        for (int fs = 0; fs < 32; ++fs)
            s += lds[(fs + tg2 * 32 + rg2 * 64) * 40 + tsub * 10 + rsub];
        int t = t_base + t_local;
        float dc = Wc[rc];
        float ny = Wc[4095 * 40 + rc];
        float sign = (t & 1) ? -1.f : 1.f;
        // y[t] = sqrt(2/n)*pairsum + (c0 + (-1)^t c_{n-1})/sqrt(n);  n=4096; x0.5 SCALING
        float g = 0.5f * (0.0220970869120796f * s + (dc + sign * ny) * (1.0f / 64.0f));
        G[t * 40 + rc] = g;
    }
}

// ---------------- Kernel 3: Wcomb[t][d] (bf16) = W_base[t][d] + sum_k G[t][k]*E[k][d]
__global__ __launch_bounds__(256) void k_wcomb(const float* __restrict__ Wb,
                                               const float* __restrict__ enc0,
                                               const float* __restrict__ enc1,
                                               const float* __restrict__ G,
                                               unsigned short* __restrict__ Wcb) {
    __shared__ float ldsE[40 * 256];
    __shared__ float ldsG[32 * 40];
    int tid = threadIdx.x;
    int d0 = blockIdx.x * 256;
    int t0 = blockIdx.y * 32;
    #pragma unroll
    for (int j = 0; j < 10; ++j) {
        int idx = tid + j * 256;   // float4 slots, 40 rows x 64 slots
        int k = idx / 64, v = idx % 64;
        const float* src = (k < 32) ? (enc0 + (size_t)k * 4096) : (enc1 + (size_t)(k - 32) * 4096);
        *(f32x4*)(ldsE + k * 256 + v * 4) = *(const f32x4*)(src + d0 + v * 4);
    }
    #pragma unroll
    for (int j = 0; j < 5; ++j) {
        int idx = tid + j * 256;   // 0..1279
        ldsG[idx] = G[(size_t)(t0 + idx / 40) * 40 + (idx % 40)];
    }
    __syncthreads();
    int dg = tid & 31, tg = tid >> 5;
    // thread covers d-cols {s*64 + dg*2, +1} for s=0..3, t rows t0+tg*4..+3
    f32x2 a[4][4];  // [s][tt]
    #pragma unroll
    for (int s = 0; s < 4; ++s)
        #pragma unroll
        for (int tt = 0; tt < 4; ++tt) a[s][tt] = (f32x2){0.f, 0.f};
    #pragma unroll 8
    for (int r = 0; r < 40; ++r) {
        f32x2 e[4];
        #pragma unroll
        for (int s = 0; s < 4; ++s)
            e[s] = *(const f32x2*)(ldsE + r * 256 + s * 64 + dg * 2);
        #pragma unroll
        for (int tt = 0; tt < 4; ++tt) {
            float g = ldsG[(tg * 4 + tt) * 40 + r];
            #pragma unroll
            for (int s = 0; s < 4; ++s)
                a[s][tt] += g * e[s];
        }
    }
    #pragma unroll
    for (int tt = 0; tt < 4; ++tt) {
        int t = t0 + tg * 4 + tt;
        #pragma unroll
        for (int s = 0; s < 4; ++s) {
            int d = d0 + s * 64 + dg * 2;
            f32x2 wv = *(const f32x2*)(Wb + (size_t)t * 4096 + d);
            f32x2 rv = a[s][tt] + wv;
            unsigned short lo = f2bf(rv[0]), hi = f2bf(rv[1]);
            *(unsigned*)(Wcb + (size_t)t * 4096 + d) = (unsigned)lo | ((unsigned)hi << 16);
        }
    }
}

// ---------------- Kernel 4: C[8192][4096] = A[8192][4096] @ B[4096][4096]^T + bias
// 256x256 tile, BK=64, 8 waves (2Mx4N), 512 threads, 128 KiB LDS (2x dbuf A+B),
// mfma_f32_16x16x32_bf16 (R4: conflict-free fragment reads, counter = 0).
// R5: pipeline reads against MFMAs. R4 was additive (5137 = 2484 MFMA + ~2800
// LDS cyc/tile) because MFMA cluster 1 looped kh inside -> consumed read #17+,
// so every wave sat through the whole 24-read burst before issuing any MFMA.
// Now: cluster 1 = kh=0 only (reads #1-12, bF first so MFMA #1 waits on read
// #5), cluster 2 = kh=1 (reads #13-24, draining on the LDS pipe UNDER cluster
// 1's ~1242 cyc of MFMA). Compiler emits per-operand lgkmcnt(N) partial waits.
// Mid-tile barrier carries lgkmcnt(0) (free by then) so the STAGE overwrite
// can never race a pending read. Sync shape otherwise unchanged from R3/R4.
__global__ __launch_bounds__(512, 2) void k_gemm(const unsigned short* __restrict__ A,
                                                 const unsigned short* __restrict__ B,
                                                 const float* __restrict__ bias,
                                                 float* __restrict__ C) {
    __shared__ __align__(16) short As[2][256 * 64];   // 64 KiB
    __shared__ __align__(16) short Bs[2][256 * 64];   // 64 KiB
    const int tid = threadIdx.x;
    const int lane = tid & 63, w = tid >> 6;
    const int wm = w >> 2, wn = w & 3;          // 2 M-waves x 4 N-waves
    const int l15 = lane & 15;                  // 16x16 fragment row-within-tile
    const int kc = lane >> 4;                   // k-chunk selector 0..3 (8 elems each)
    const int sk = lane & 7;                    // XOR key (== row&7: tile bases are 16-mult)

    // XCD-aware bijective swizzle: 512 blocks, 512 % 8 == 0
    int bid = blockIdx.x;
    int swz = (bid & 7) * 64 + (bid >> 3);
    int m0 = (swz >> 4) * 256;                  // 32 M-tiles
    int n0 = (swz & 15) * 256;                  // 16 N-tiles

    // staging geometry: one GL2LDS(512 threads) = 64 rows x 64 cols (8 KiB)
    // LDS slot (row, c) holds global (row, c ^ (row&7)) via pre-swizzled source.
    const int srow = w * 8 + (lane >> 3);
    const int scg  = (lane & 7) ^ ((lane >> 3) & 7);
    const unsigned short* Ag = A + (size_t)(m0 + srow) * 4096 + scg * 8;
    const unsigned short* Bg = B + (size_t)(n0 + srow) * 4096 + scg * 8;

#define STAGE(buf, kt) do { \
    _Pragma("unroll") \
    for (int c = 0; c < 4; ++c) { \
        GL2LDS(Ag + (size_t)(c * 64) * 4096 + (kt), &As[buf][(c * 64 + w * 8) * 64]); \
        GL2LDS(Bg + (size_t)(c * 64) * 4096 + (kt), &Bs[buf][(c * 64 + w * 8) * 64]); \
    } \
} while (0)

    // fragment read offsets (shorts): A m-tile mt rows wm*128+mt*16+l15;
    // B n-tile nt rows wn*64+nt*16+l15; k-half kh slot = ((kh*4+kc)^sk)*8
    int aoff[8], boff[4];
    #pragma unroll
    for (int mt = 0; mt < 8; ++mt) aoff[mt] = (wm * 128 + mt * 16 + l15) * 64;
    #pragma unroll
    for (int nt = 0; nt < 4; ++nt) boff[nt] = (wn * 64 + nt * 16 + l15) * 64;
    const int s0 = ((0 + kc) ^ sk) * 8;
    const int s1 = ((4 + kc) ^ sk) * 8;

    f32x4 acc[8][4];
    #pragma unroll
    for (int mt = 0; mt < 8; ++mt)
        #pragma unroll
        for (int nt = 0; nt < 4; ++nt)
            #pragma unroll
            for (int r = 0; r < 4; ++r) acc[mt][nt][r] = 0.f;

// One K-tile on buffer CB. Stages tile T+2 (k = kt+128) into CB (same parity).
// WAITK: 8 = steady boundary, 0 = final drain, -1 = none (last tile).
// Read order == consumption order: bF[0..3][kh0], aF[0..7][kh0], then kh1 group.
// Cluster 1 (kh=0) depends only on reads #1-12; kh=1 reads drain under it.
#define TILE_BODY(CB, kt, DO_STAGE, WAITK) do { \
    bf16x8 aF[8][2], bF[4][2]; \
    _Pragma("unroll") \
    for (int nt = 0; nt < 4; ++nt) \
        bF[nt][0] = *(const bf16x8*)&Bs[CB][boff[nt] + s0]; \
    _Pragma("unroll") \
    for (int mt = 0; mt < 8; ++mt) \
        aF[mt][0] = *(const bf16x8*)&As[CB][aoff[mt] + s0]; \
    _Pragma("unroll") \
    for (int nt = 0; nt < 4; ++nt) \
        bF[nt][1] = *(const bf16x8*)&Bs[CB][boff[nt] + s1]; \
    _Pragma("unroll") \
    for (int mt = 0; mt < 8; ++mt) \
        aF[mt][1] = *(const bf16x8*)&As[CB][aoff[mt] + s1]; \
    __builtin_amdgcn_s_setprio(1); \
    _Pragma("unroll") \
    for (int mt = 0; mt < 8; ++mt) \
        _Pragma("unroll") \
        for (int nt = 0; nt < 4; ++nt) \
            acc[mt][nt] = __builtin_amdgcn_mfma_f32_16x16x32_bf16(aF[mt][0], bF[nt][0], acc[mt][nt], 0, 0, 0); \
    __builtin_amdgcn_s_setprio(0); \
    asm volatile("s_waitcnt lgkmcnt(0)\n\ts_barrier" ::: "memory"); \
    if (DO_STAGE) STAGE(CB, (kt) + 128); \
    __builtin_amdgcn_s_setprio(1); \
    _Pragma("unroll") \
    for (int mt = 0; mt < 8; ++mt) \
        _Pragma("unroll") \
        for (int nt = 0; nt < 4; ++nt) \
            acc[mt][nt] = __builtin_amdgcn_mfma_f32_16x16x32_bf16(aF[mt][1], bF[nt][1], acc[mt][nt], 0, 0, 0); \
    __builtin_amdgcn_s_setprio(0); \
    if ((WAITK) == 8) { \
        asm volatile("s_waitcnt vmcnt(8)\n\ts_barrier" ::: "memory"); \
    } else if ((WAITK) == 0) { \
        asm volatile("s_waitcnt vmcnt(0)\n\ts_barrier" ::: "memory"); \
    } \
} while (0)

    // prologue: stage tiles 0 and 1; vmcnt(8) -> tile0 ready, tile1 in flight
    STAGE(0, 0);
    STAGE(1, 64);
    asm volatile("s_waitcnt vmcnt(8)\n\ts_barrier" ::: "memory");

    for (int i = 0; i < 31; ++i) {
        int kt = i * 128;
        TILE_BODY(0, kt, true, 8);        // tile 2i:   stage 2i+2 -> buf0
        TILE_BODY(1, kt + 64, true, 8);   // tile 2i+1: stage 2i+3 -> buf1
    }
    TILE_BODY(0, 62 * 64, false, 0);      // tile 62: drain (tile 63's loads)
    TILE_BODY(1, 63 * 64, false, -1);     // tile 63: no wait needed
#undef TILE_BODY
#undef STAGE

    // C/D layout 16x16 (m89/m91): col = lane&15, row = (lane>>4)*4 + reg
    const int r4 = (lane >> 4) * 4;
    float bv[4];
    #pragma unroll
    for (int nt = 0; nt < 4; ++nt) bv[nt] = bias[n0 + wn * 64 + nt * 16 + l15];
    #pragma unroll
    for (int mt = 0; mt < 8; ++mt) {
        #pragma unroll
        for (int nt = 0; nt < 4; ++nt) {
            #pragma unroll
            for (int r = 0; r < 4; ++r) {
                int row = m0 + wm * 128 + mt * 16 + r4 + r;
                C[(size_t)row * 4096 + n0 + wn * 64 + nt * 16 + l15] = acc[mt][nt][r] + bv[nt];
            }
        }
    }
}

extern "C" void kernel_launch(void* const* d_in, const int* in_sizes, int n_in,
                              void* d_out, int out_size, void* d_ws, size_t ws_size,
                              hipStream_t stream) {
    const float* x   = (const float*)d_in[0];   // [4,2048,4096]
    const float* Wb  = (const float*)d_in[1];   // [4096,4096]
    const float* bb  = (const float*)d_in[2];   // [4096]
    const float* e0  = (const float*)d_in[3];   // [32,4096]
    const float* e1  = (const float*)d_in[4];   // [8,4096]
    const float* c0  = (const float*)d_in[5];   // [3,4096,32]
    const float* c1  = (const float*)d_in[6];   // [3,4096,8]
    const int*   m0  = (const int*)d_in[7];     // [3,4096,32] bool->int32
    const int*   m1  = (const int*)d_in[8];     // [3,4096,8]
    float* out = (float*)d_out;                 // [4,2048,4096]

    char* ws = (char*)d_ws;
    unsigned short* xb  = (unsigned short*)ws;              // 67108864 B
    float* Wc           = (float*)(ws + 67108864);          // 655360 B
    float* G            = (float*)(ws + 67764224);          // 655360 B
    unsigned short* Wcb = (unsigned short*)(ws + 68419584); // 33554432 B

    k_prep <<<17024, 256, 0, stream>>>(c0, c1, m0, m1, Wc, x, xb);
    k_gmat <<<512, 256, 0, stream>>>(Wc, G);
    k_wcomb<<<dim3(16, 128), 256, 0, stream>>>(Wb, e0, e1, G, Wcb);
    k_gemm <<<512, 512, 0, stream>>>(xb, Wcb, bb, out);
}